// Round 9
// baseline (553.003 us; speedup 1.0000x reference)
//
#include <hip/hip_runtime.h>
#include <math.h>

#define NB 2048
#define CINC 10
#define HID 20
#define NG 5
#define GDIM 100   // NG*HID
#define GH 15
#define GW 15
#define BW 3       // batch elems per wave (3*20 = 60 active lanes)

typedef _Float16 half2v __attribute__((ext_vector_type(2)));
typedef _Float16 half4v __attribute__((ext_vector_type(4)));
typedef _Float16 half8v __attribute__((ext_vector_type(8)));

#if defined(__has_builtin)
#if __has_builtin(__builtin_amdgcn_fdot2)
#define HAVE_FDOT2 1
#endif
#endif

__device__ __forceinline__ float fdot2f(half2v a, half2v b, float c) {
#ifdef HAVE_FDOT2
    return __builtin_amdgcn_fdot2(a, b, c, false);
#else
    return c + (float)a[0] * (float)b[0] + (float)a[1] * (float)b[1];
#endif
}

__device__ __forceinline__ float sigf(float x) {
    return __builtin_amdgcn_rcpf(1.f + __expf(-x));
}
__device__ __forceinline__ float tanhfast(float x) {
    // overflow-safe: e = exp(-2|x|) in (0,1], restore sign
    float ax = fabsf(x);
    float e = __expf(-2.f * ax);
    float t = (1.f - e) * __builtin_amdgcn_rcpf(1.f + e);
    return copysignf(t, x);
}

#define SV8(v, a, b) ((half2v)__builtin_shufflevector(v, v, a, b))
#define SV4(v, a, b) ((half2v)__builtin_shufflevector(v, v, a, b))

// One LSTM cell: reads up-h (24-half slot), left-h, x (16-half slot), cu; updates CLV; outputs HN/CN.
#define CELL(HUP, HLP, FXP, CU, CLV, HN, CN) do {                                   \
    const _Float16* hup_ = (HUP); const _Float16* hlp_ = (HLP);                     \
    const _Float16* fxp_ = (FXP);                                                   \
    half8v u0_ = *(const half8v*)(hup_);                                            \
    half8v u1_ = *(const half8v*)(hup_ + 8);                                        \
    half4v u2_ = *(const half4v*)(hup_ + 16);                                       \
    half8v l0_ = *(const half8v*)(hlp_);                                            \
    half8v l1_ = *(const half8v*)(hlp_ + 8);                                        \
    half4v l2_ = *(const half4v*)(hlp_ + 16);                                       \
    half8v x0_ = *(const half8v*)(fxp_);                                            \
    half4v x1_ = *(const half4v*)(fxp_ + 8);                                        \
    half2v up_[10] = { SV8(u0_,0,1),SV8(u0_,2,3),SV8(u0_,4,5),SV8(u0_,6,7),         \
                       SV8(u1_,0,1),SV8(u1_,2,3),SV8(u1_,4,5),SV8(u1_,6,7),         \
                       SV4(u2_,0,1),SV4(u2_,2,3) };                                 \
    half2v lf_[10] = { SV8(l0_,0,1),SV8(l0_,2,3),SV8(l0_,4,5),SV8(l0_,6,7),         \
                       SV8(l1_,0,1),SV8(l1_,2,3),SV8(l1_,4,5),SV8(l1_,6,7),         \
                       SV4(l2_,0,1),SV4(l2_,2,3) };                                 \
    half2v xp_[6]  = { SV8(x0_,0,1),SV8(x0_,2,3),SV8(x0_,4,5),SV8(x0_,6,7),         \
                       SV4(x1_,0,1),SV4(x1_,2,3) };                                 \
    float acc_[NG];                                                                 \
    _Pragma("unroll") for (int g_ = 0; g_ < NG; ++g_) acc_[g_] = bgr[g_];           \
    _Pragma("unroll") for (int m_ = 0; m_ < 10; ++m_) {                             \
        _Pragma("unroll") for (int g_ = 0; g_ < NG; ++g_)                           \
            acc_[g_] = fdot2f(up_[m_], wU[m_][g_], acc_[g_]); }                     \
    _Pragma("unroll") for (int m_ = 0; m_ < 10; ++m_) {                             \
        _Pragma("unroll") for (int g_ = 0; g_ < NG; ++g_)                           \
            acc_[g_] = fdot2f(lf_[m_], wL[m_][g_], acc_[g_]); }                     \
    _Pragma("unroll") for (int w_ = 0; w_ < 6; ++w_) {                              \
        _Pragma("unroll") for (int g_ = 0; g_ < NG; ++g_)                           \
            acc_[g_] = fdot2f(xp_[w_], wX2[w_][g_], acc_[g_]); }                    \
    float gi_ = sigf(acc_[0]);                                                      \
    float g1_ = sigf(acc_[1]);                                                      \
    float g2_ = sigf(acc_[2]);                                                      \
    float zz_ = tanhfast(acc_[3]);                                                  \
    float go_ = sigf(acc_[4]);                                                      \
    (CN) = g1_ * (CU) + g2_ * (CLV) + gi_ * zz_;                                    \
    (HN) = go_ * tanhfast(CN);                                                      \
    (CLV) = (CN);                                                                   \
} while (0)

// ---------------- Kernel 1: conv3x3 + bias + maxpool2x2 + tanh -> f16 pairs ----------------
__global__ __launch_bounds__(256) void conv_pool_tanh(
    const float* __restrict__ x,
    const float* __restrict__ conv_w,
    const float* __restrict__ conv_b,
    half2v* __restrict__ featH)
{
    __shared__ float wl[270];
    __shared__ float bl[10];
    int tid = threadIdx.x;
    for (int e = tid; e < 270; e += 256) wl[e] = conv_w[e];
    if (tid < 10) bl[tid] = conv_b[tid];
    __syncthreads();
    int gid = blockIdx.x * 256 + tid;
    if (gid >= NB * 225) return;
    int b = gid / 225;
    int r = gid % 225;
    int i = r / 15, j = r % 15;
    const float* xb = x + (size_t)b * 3 * 1024;

    float win[3][4][4];
    #pragma unroll
    for (int ic = 0; ic < 3; ++ic)
        #pragma unroll
        for (int rr = 0; rr < 4; ++rr)
            #pragma unroll
            for (int cc = 0; cc < 4; ++cc)
                win[ic][rr][cc] = xb[ic * 1024 + (2 * i + rr) * 32 + (2 * j + cc)];

    float vals[10];
    #pragma unroll
    for (int oc = 0; oc < CINC; ++oc) {
        float a00, a01, a10, a11;
        a00 = a01 = a10 = a11 = bl[oc];
        #pragma unroll
        for (int ic = 0; ic < 3; ++ic)
            #pragma unroll
            for (int kr = 0; kr < 3; ++kr)
                #pragma unroll
                for (int kc = 0; kc < 3; ++kc) {
                    float w = wl[(oc * 3 + ic) * 9 + kr * 3 + kc];
                    a00 += win[ic][kr][kc]         * w;
                    a01 += win[ic][kr][kc + 1]     * w;
                    a10 += win[ic][kr + 1][kc]     * w;
                    a11 += win[ic][kr + 1][kc + 1] * w;
                }
        float m = fmaxf(fmaxf(a00, a01), fmaxf(a10, a11));
        vals[oc] = tanhfast(m);
    }
    half2v* fo = featH + (size_t)gid * 6;
    half2v w0; w0[0] = (_Float16)vals[0]; w0[1] = (_Float16)vals[1]; fo[0] = w0;
    half2v w1; w1[0] = (_Float16)vals[2]; w1[1] = (_Float16)vals[3]; fo[1] = w1;
    half2v w2; w2[0] = (_Float16)vals[4]; w2[1] = (_Float16)0.f;     fo[2] = w2;
    half2v w3; w3[0] = (_Float16)vals[5]; w3[1] = (_Float16)vals[6]; fo[3] = w3;
    half2v w4; w4[0] = (_Float16)vals[7]; w4[1] = (_Float16)vals[8]; fo[4] = w4;
    half2v w5; w5[0] = (_Float16)vals[9]; w5[1] = (_Float16)0.f;     fo[5] = w5;
}

// ---------------- Kernel 2: barrier-free wave-private MD-LSTM scan, row-pair skewed ----------------
// Block = 1 wave = (direction, 3-batch tile). lane = (b<3, j<20).
// Processes rows in skewed pairs: step tt runs cell (i0, tt) and cell (i1, tt-2) — two
// independent dependence chains per wave. In-place LDS: c single-buffer (lane-private
// read-then-overwrite), h two ping-pong row buffers (A overwrites its up-slot in place).
__global__ __launch_bounds__(64, 3) void mdlstm_scan(
    const _Float16* __restrict__ featF,   // [B,225,12] halves (packed 16/slot)
    const float* __restrict__ Wx,         // [4,10,100]
    const float* __restrict__ Whu,        // [4,20,100]
    const float* __restrict__ Whl,        // [4,20,100]
    const float* __restrict__ bg,         // [4,100]
    float* __restrict__ corners)          // [B,80]
{
    int t = threadIdx.x;
    int b = t / HID;              // 0..2 active
    int j = t % HID;
    bool act = (t < BW * HID);
    int bl = act ? b : 0;
    int d = blockIdx.y;
    int bglob = blockIdx.x * BW + b;
    bool bval = act && (bglob < NB);
    int fh = (d == 1 || d == 3);
    int fw = (d == 2 || d == 3);

    // ---- f16-packed weights in registers ----
    half2v wU[10][NG], wL[10][NG], wX2[6][NG];
    {
        const float* WU = Whu + d * HID * GDIM;
        const float* WL = Whl + d * HID * GDIM;
        #pragma unroll
        for (int m = 0; m < 10; ++m)
            #pragma unroll
            for (int g = 0; g < NG; ++g) {
                int cidx = g * HID + j;
                half2v w; w[0] = (_Float16)WU[(2*m)*GDIM + cidx]; w[1] = (_Float16)WU[(2*m+1)*GDIM + cidx];
                wU[m][g] = w;
                half2v v; v[0] = (_Float16)WL[(2*m)*GDIM + cidx]; v[1] = (_Float16)WL[(2*m+1)*GDIM + cidx];
                wL[m][g] = v;
            }
        const int cha[6] = {0, 2, 4, 5, 7, 9};
        const int chb[6] = {1, 3, -1, 6, 8, -1};
        const float* WXp = Wx + d * CINC * GDIM;
        #pragma unroll
        for (int w = 0; w < 6; ++w)
            #pragma unroll
            for (int g = 0; g < NG; ++g) {
                int cidx = g * HID + j;
                half2v v;
                v[0] = (_Float16)WXp[cha[w] * GDIM + cidx];
                v[1] = (chb[w] >= 0) ? (_Float16)WXp[chb[w] * GDIM + cidx] : (_Float16)0.f;
                wX2[w][g] = v;
            }
    }
    float bgr[NG];
    #pragma unroll
    for (int g = 0; g < NG; ++g) bgr[g] = bg[d * GDIM + g * HID + j];

    // ---- LDS (11.1 KB) ----
    __shared__ _Float16 hBuf[2][GW + 1][BW][24];  // 4.6 KB; slot 0 = permanent zeros
    __shared__ float    cBuf[GW][BW][HID];        // 3.6 KB; in-place per column
    __shared__ _Float16 fr[2][GW][BW][16];        // 2.9 KB; two staged feat rows

    for (int e = t; e < 2 * (GW + 1) * BW * 24; e += 64) (&hBuf[0][0][0][0])[e] = (_Float16)0.f;
    for (int e = t; e < GW * BW * HID; e += 64) (&cBuf[0][0][0])[e] = 0.f;

    int uv = 0;
    for (int r = 0; r < 7; ++r) {
        int i0 = 2 * r, i1 = 2 * r + 1;
        // stage feat rows i0, i1 (W-flip applied)
        {
            int fi0 = fh ? (GH - 1 - i0) : i0;
            int fi1 = fh ? (GH - 1 - i1) : i1;
            for (int e = t; e < 2 * GW * BW * 6; e += 64) {
                int fb  = e / (GW * BW * 6);
                int rem = e % (GW * BW * 6);
                int col = rem / (BW * 6);
                int r2  = rem % (BW * 6);
                int bb  = r2 / 6, w = r2 % 6;
                int bs  = blockIdx.x * BW + bb; if (bs >= NB) bs = NB - 1;
                int fcol = fw ? (GW - 1 - col) : col;
                int fi  = fb ? fi1 : fi0;
                ((unsigned*)fr)[(fb * GW * BW + col * BW + bb) * 8 + w] =
                    ((const unsigned*)featF)[((size_t)bs * 225 + fi * 15 + fcol) * 6 + w];
            }
        }
        _Float16* U = &hBuf[uv][0][0][0];       // holds row i0-1; overwritten in place with row i0
        _Float16* V = &hBuf[uv ^ 1][0][0][0];   // receives row i1
        float clA = 0.f, clB = 0.f;
        for (int tt = 0; tt < GW + 2; ++tt) {
            if (tt < GW) {   // cell A = (i0, tt)
                float cu = cBuf[tt][bl][j];      // row i0-1 value
                float hn, cn;
                CELL(U + ((tt + 1) * BW + bl) * 24,   // up (row i0-1), overwritten below
                     U + (tt * BW + bl) * 24,         // left (row i0, written at tt-1; slot0=0)
                     &fr[0][tt][bl][0], cu, clA, hn, cn);
                if (act) {
                    U[((tt + 1) * BW + bl) * 24 + j] = (_Float16)hn;
                    cBuf[tt][bl][j] = cn;
                }
            }
            if (tt >= 2) {   // cell B = (i1, tt-2)
                int u = tt - 2;
                float cu = cBuf[u][bl][j];       // row i0 value (A wrote it 2 steps ago)
                float hn, cn;
                CELL(U + ((u + 1) * BW + bl) * 24,    // up (row i0)
                     V + (u * BW + bl) * 24,          // left (row i1, written prev step)
                     &fr[1][u][bl][0], cu, clB, hn, cn);
                if (act) {
                    V[((u + 1) * BW + bl) * 24 + j] = (_Float16)hn;
                    cBuf[u][bl][j] = cn;
                }
            }
        }
        uv ^= 1;
    }
    // ---- solo row 14 ----
    {
        int fi0 = fh ? 0 : (GH - 1);
        for (int e = t; e < GW * BW * 6; e += 64) {
            int col = e / (BW * 6);
            int r2  = e % (BW * 6);
            int bb  = r2 / 6, w = r2 % 6;
            int bs  = blockIdx.x * BW + bb; if (bs >= NB) bs = NB - 1;
            int fcol = fw ? (GW - 1 - col) : col;
            ((unsigned*)fr)[(col * BW + bb) * 8 + w] =
                ((const unsigned*)featF)[((size_t)bs * 225 + fi0 * 15 + fcol) * 6 + w];
        }
        _Float16* U = &hBuf[uv][0][0][0];   // holds row 13
        float clA = 0.f;
        for (int tt = 0; tt < GW; ++tt) {
            float cu = cBuf[tt][bl][j];
            float hn, cn;
            CELL(U + ((tt + 1) * BW + bl) * 24,
                 U + (tt * BW + bl) * 24,
                 &fr[0][tt][bl][0], cu, clA, hn, cn);
            if (act) U[((tt + 1) * BW + bl) * 24 + j] = (_Float16)hn;
            if (bval && tt == GW - 1)
                corners[(size_t)bglob * 80 + d * HID + j] = hn;
        }
    }
}

// ---------------- Kernel 3: final FC [B,80] @ [80,10] + b ----------------
__global__ __launch_bounds__(256) void fc_kernel(
    const float* __restrict__ corners, // [B,80]
    const float* __restrict__ fc_w,    // [80,10]
    const float* __restrict__ fc_b,    // [10]
    float* __restrict__ out)           // [B,10]
{
    __shared__ float w[800];
    __shared__ float bb[10];
    int t = threadIdx.x;
    for (int e = t; e < 800; e += 256) w[e] = fc_w[e];
    if (t < 10) bb[t] = fc_b[t];
    __syncthreads();
    int gid = blockIdx.x * 256 + t;
    if (gid >= NB * 10) return;
    int b = gid / 10, o = gid % 10;
    float acc = bb[o];
    #pragma unroll 8
    for (int k = 0; k < 80; ++k)
        acc += corners[(size_t)b * 80 + k] * w[k * 10 + o];
    out[gid] = acc;
}

// ---------------- launcher ----------------
extern "C" void kernel_launch(void* const* d_in, const int* in_sizes, int n_in,
                              void* d_out, int out_size, void* d_ws, size_t ws_size,
                              hipStream_t stream) {
    const float* x      = (const float*)d_in[0];
    const float* conv_w = (const float*)d_in[1];
    const float* conv_b = (const float*)d_in[2];
    const float* Wx     = (const float*)d_in[3];
    const float* Whu    = (const float*)d_in[4];
    const float* Whl    = (const float*)d_in[5];
    const float* bg     = (const float*)d_in[6];
    const float* fc_w   = (const float*)d_in[7];
    const float* fc_b   = (const float*)d_in[8];
    float* out = (float*)d_out;

    half2v*    featH = (half2v*)d_ws;                       // B*225*6 half2 = 11.06 MB
    _Float16*  featF = (_Float16*)d_ws;
    float* corners   = (float*)d_ws + (size_t)NB * 225 * 6; // B*80 floats

    conv_pool_tanh<<<dim3((NB * 225 + 255) / 256), 256, 0, stream>>>(x, conv_w, conv_b, featH);
    mdlstm_scan<<<dim3((NB + BW - 1) / BW, 4), 64, 0, stream>>>(featF, Wx, Whu, Whl, bg, corners);
    fc_kernel<<<dim3((NB * 10 + 255) / 256), 256, 0, stream>>>(corners, fc_w, fc_b, out);
}

// Round 10
// 451.404 us; speedup vs baseline: 1.2251x; 1.2251x over previous
//
#include <hip/hip_runtime.h>
#include <math.h>

#define NB 2048
#define CINC 10
#define HID 20
#define NG 5
#define GDIM 100   // NG*HID
#define GH 15
#define GW 15
#define BW 3       // batch elems per wave (3*20 = 60 active lanes)

typedef _Float16 half2v __attribute__((ext_vector_type(2)));
typedef _Float16 half4v __attribute__((ext_vector_type(4)));
typedef _Float16 half8v __attribute__((ext_vector_type(8)));

#if defined(__has_builtin)
#if __has_builtin(__builtin_amdgcn_fdot2)
#define HAVE_FDOT2 1
#endif
#endif

__device__ __forceinline__ float fdot2f(half2v a, half2v b, float c) {
#ifdef HAVE_FDOT2
    return __builtin_amdgcn_fdot2(a, b, c, false);
#else
    return c + (float)a[0] * (float)b[0] + (float)a[1] * (float)b[1];
#endif
}

__device__ __forceinline__ float sigf(float x) {
    return __builtin_amdgcn_rcpf(1.f + __expf(-x));
}
__device__ __forceinline__ float tanhfast(float x) {
    // overflow-safe: e = exp(-2|x|) in (0,1], restore sign
    float ax = fabsf(x);
    float e = __expf(-2.f * ax);
    float t = (1.f - e) * __builtin_amdgcn_rcpf(1.f + e);
    return copysignf(t, x);
}

#define SV8(v, a, b) ((half2v)__builtin_shufflevector(v, v, a, b))
#define SV4(v, a, b) ((half2v)__builtin_shufflevector(v, v, a, b))

// One LSTM cell: reads up-h (24-half slot), left-h, x (16-half slot), cu; updates CLV; outputs HN/CN.
#define CELL(HUP, HLP, FXP, CU, CLV, HN, CN) do {                                   \
    const _Float16* hup_ = (HUP); const _Float16* hlp_ = (HLP);                     \
    const _Float16* fxp_ = (FXP);                                                   \
    half8v u0_ = *(const half8v*)(hup_);                                            \
    half8v u1_ = *(const half8v*)(hup_ + 8);                                        \
    half4v u2_ = *(const half4v*)(hup_ + 16);                                       \
    half8v l0_ = *(const half8v*)(hlp_);                                            \
    half8v l1_ = *(const half8v*)(hlp_ + 8);                                        \
    half4v l2_ = *(const half4v*)(hlp_ + 16);                                       \
    half8v x0_ = *(const half8v*)(fxp_);                                            \
    half4v x1_ = *(const half4v*)(fxp_ + 8);                                        \
    half2v up_[10] = { SV8(u0_,0,1),SV8(u0_,2,3),SV8(u0_,4,5),SV8(u0_,6,7),         \
                       SV8(u1_,0,1),SV8(u1_,2,3),SV8(u1_,4,5),SV8(u1_,6,7),         \
                       SV4(u2_,0,1),SV4(u2_,2,3) };                                 \
    half2v lf_[10] = { SV8(l0_,0,1),SV8(l0_,2,3),SV8(l0_,4,5),SV8(l0_,6,7),         \
                       SV8(l1_,0,1),SV8(l1_,2,3),SV8(l1_,4,5),SV8(l1_,6,7),         \
                       SV4(l2_,0,1),SV4(l2_,2,3) };                                 \
    half2v xp_[6]  = { SV8(x0_,0,1),SV8(x0_,2,3),SV8(x0_,4,5),SV8(x0_,6,7),         \
                       SV4(x1_,0,1),SV4(x1_,2,3) };                                 \
    float acc_[NG];                                                                 \
    _Pragma("unroll") for (int g_ = 0; g_ < NG; ++g_) acc_[g_] = bgr[g_];           \
    _Pragma("unroll") for (int m_ = 0; m_ < 10; ++m_) {                             \
        _Pragma("unroll") for (int g_ = 0; g_ < NG; ++g_)                           \
            acc_[g_] = fdot2f(up_[m_], wU[m_][g_], acc_[g_]); }                     \
    _Pragma("unroll") for (int m_ = 0; m_ < 10; ++m_) {                             \
        _Pragma("unroll") for (int g_ = 0; g_ < NG; ++g_)                           \
            acc_[g_] = fdot2f(lf_[m_], wL[m_][g_], acc_[g_]); }                     \
    _Pragma("unroll") for (int w_ = 0; w_ < 6; ++w_) {                              \
        _Pragma("unroll") for (int g_ = 0; g_ < NG; ++g_)                           \
            acc_[g_] = fdot2f(xp_[w_], wX2[w_][g_], acc_[g_]); }                    \
    float gi_ = sigf(acc_[0]);                                                      \
    float g1_ = sigf(acc_[1]);                                                      \
    float g2_ = sigf(acc_[2]);                                                      \
    float zz_ = tanhfast(acc_[3]);                                                  \
    float go_ = sigf(acc_[4]);                                                      \
    (CN) = g1_ * (CU) + g2_ * (CLV) + gi_ * zz_;                                    \
    (HN) = go_ * tanhfast(CN);                                                      \
    (CLV) = (CN);                                                                   \
} while (0)

// ---------------- Kernel 1: conv3x3 + bias + maxpool2x2 + tanh -> f16 pairs ----------------
__global__ __launch_bounds__(256) void conv_pool_tanh(
    const float* __restrict__ x,
    const float* __restrict__ conv_w,
    const float* __restrict__ conv_b,
    half2v* __restrict__ featH)
{
    __shared__ float wl[270];
    __shared__ float bl[10];
    int tid = threadIdx.x;
    for (int e = tid; e < 270; e += 256) wl[e] = conv_w[e];
    if (tid < 10) bl[tid] = conv_b[tid];
    __syncthreads();
    int gid = blockIdx.x * 256 + tid;
    if (gid >= NB * 225) return;
    int b = gid / 225;
    int r = gid % 225;
    int i = r / 15, j = r % 15;
    const float* xb = x + (size_t)b * 3 * 1024;

    float win[3][4][4];
    #pragma unroll
    for (int ic = 0; ic < 3; ++ic)
        #pragma unroll
        for (int rr = 0; rr < 4; ++rr)
            #pragma unroll
            for (int cc = 0; cc < 4; ++cc)
                win[ic][rr][cc] = xb[ic * 1024 + (2 * i + rr) * 32 + (2 * j + cc)];

    float vals[10];
    #pragma unroll
    for (int oc = 0; oc < CINC; ++oc) {
        float a00, a01, a10, a11;
        a00 = a01 = a10 = a11 = bl[oc];
        #pragma unroll
        for (int ic = 0; ic < 3; ++ic)
            #pragma unroll
            for (int kr = 0; kr < 3; ++kr)
                #pragma unroll
                for (int kc = 0; kc < 3; ++kc) {
                    float w = wl[(oc * 3 + ic) * 9 + kr * 3 + kc];
                    a00 += win[ic][kr][kc]         * w;
                    a01 += win[ic][kr][kc + 1]     * w;
                    a10 += win[ic][kr + 1][kc]     * w;
                    a11 += win[ic][kr + 1][kc + 1] * w;
                }
        float m = fmaxf(fmaxf(a00, a01), fmaxf(a10, a11));
        vals[oc] = tanhfast(m);
    }
    half2v* fo = featH + (size_t)gid * 6;
    half2v w0; w0[0] = (_Float16)vals[0]; w0[1] = (_Float16)vals[1]; fo[0] = w0;
    half2v w1; w1[0] = (_Float16)vals[2]; w1[1] = (_Float16)vals[3]; fo[1] = w1;
    half2v w2; w2[0] = (_Float16)vals[4]; w2[1] = (_Float16)0.f;     fo[2] = w2;
    half2v w3; w3[0] = (_Float16)vals[5]; w3[1] = (_Float16)vals[6]; fo[3] = w3;
    half2v w4; w4[0] = (_Float16)vals[7]; w4[1] = (_Float16)vals[8]; fo[4] = w4;
    half2v w5; w5[0] = (_Float16)vals[9]; w5[1] = (_Float16)0.f;     fo[5] = w5;
}

// ---------------- Kernel 2: barrier-free wave-private MD-LSTM scan, row-pair skewed ----------------
// Block = 1 wave = (direction, 3-batch tile). lane = (b<3, j<20).
// Processes rows in skewed pairs: step tt runs cell (i0, tt) and cell (i1, tt-2) — two
// independent dependence chains per wave. In-place LDS: c single-buffer (lane-private
// read-then-overwrite), h two ping-pong row buffers (A overwrites its up-slot in place).
// NOTE: no min-waves clause — round 9 showed (64,3)'s 170-VGPR cap makes LLVM demote
// the 130-reg weight arrays to scratch (VGPR=84, WRITE_SIZE 82 MB). Let it take ~200.
__global__ __launch_bounds__(64) void mdlstm_scan(
    const _Float16* __restrict__ featF,   // [B,225,12] halves (packed 16/slot)
    const float* __restrict__ Wx,         // [4,10,100]
    const float* __restrict__ Whu,        // [4,20,100]
    const float* __restrict__ Whl,        // [4,20,100]
    const float* __restrict__ bg,         // [4,100]
    float* __restrict__ corners)          // [B,80]
{
    int t = threadIdx.x;
    int b = t / HID;              // 0..2 active
    int j = t % HID;
    bool act = (t < BW * HID);
    int bl = act ? b : 0;
    int d = blockIdx.y;
    int bglob = blockIdx.x * BW + b;
    bool bval = act && (bglob < NB);
    int fh = (d == 1 || d == 3);
    int fw = (d == 2 || d == 3);

    // ---- f16-packed weights in registers ----
    half2v wU[10][NG], wL[10][NG], wX2[6][NG];
    {
        const float* WU = Whu + d * HID * GDIM;
        const float* WL = Whl + d * HID * GDIM;
        #pragma unroll
        for (int m = 0; m < 10; ++m)
            #pragma unroll
            for (int g = 0; g < NG; ++g) {
                int cidx = g * HID + j;
                half2v w; w[0] = (_Float16)WU[(2*m)*GDIM + cidx]; w[1] = (_Float16)WU[(2*m+1)*GDIM + cidx];
                wU[m][g] = w;
                half2v v; v[0] = (_Float16)WL[(2*m)*GDIM + cidx]; v[1] = (_Float16)WL[(2*m+1)*GDIM + cidx];
                wL[m][g] = v;
            }
        const int cha[6] = {0, 2, 4, 5, 7, 9};
        const int chb[6] = {1, 3, -1, 6, 8, -1};
        const float* WXp = Wx + d * CINC * GDIM;
        #pragma unroll
        for (int w = 0; w < 6; ++w)
            #pragma unroll
            for (int g = 0; g < NG; ++g) {
                int cidx = g * HID + j;
                half2v v;
                v[0] = (_Float16)WXp[cha[w] * GDIM + cidx];
                v[1] = (chb[w] >= 0) ? (_Float16)WXp[chb[w] * GDIM + cidx] : (_Float16)0.f;
                wX2[w][g] = v;
            }
    }
    float bgr[NG];
    #pragma unroll
    for (int g = 0; g < NG; ++g) bgr[g] = bg[d * GDIM + g * HID + j];

    // ---- LDS (11.1 KB) ----
    __shared__ _Float16 hBuf[2][GW + 1][BW][24];  // 4.6 KB; slot 0 = permanent zeros
    __shared__ float    cBuf[GW][BW][HID];        // 3.6 KB; in-place per column
    __shared__ _Float16 fr[2][GW][BW][16];        // 2.9 KB; two staged feat rows

    for (int e = t; e < 2 * (GW + 1) * BW * 24; e += 64) (&hBuf[0][0][0][0])[e] = (_Float16)0.f;
    for (int e = t; e < GW * BW * HID; e += 64) (&cBuf[0][0][0])[e] = 0.f;

    int uv = 0;
    for (int r = 0; r < 7; ++r) {
        int i0 = 2 * r, i1 = 2 * r + 1;
        // stage feat rows i0, i1 (W-flip applied)
        {
            int fi0 = fh ? (GH - 1 - i0) : i0;
            int fi1 = fh ? (GH - 1 - i1) : i1;
            for (int e = t; e < 2 * GW * BW * 6; e += 64) {
                int fb  = e / (GW * BW * 6);
                int rem = e % (GW * BW * 6);
                int col = rem / (BW * 6);
                int r2  = rem % (BW * 6);
                int bb  = r2 / 6, w = r2 % 6;
                int bs  = blockIdx.x * BW + bb; if (bs >= NB) bs = NB - 1;
                int fcol = fw ? (GW - 1 - col) : col;
                int fi  = fb ? fi1 : fi0;
                ((unsigned*)fr)[(fb * GW * BW + col * BW + bb) * 8 + w] =
                    ((const unsigned*)featF)[((size_t)bs * 225 + fi * 15 + fcol) * 6 + w];
            }
        }
        _Float16* U = &hBuf[uv][0][0][0];       // holds row i0-1; overwritten in place with row i0
        _Float16* V = &hBuf[uv ^ 1][0][0][0];   // receives row i1
        float clA = 0.f, clB = 0.f;
        for (int tt = 0; tt < GW + 2; ++tt) {
            if (tt < GW) {   // cell A = (i0, tt)
                float cu = cBuf[tt][bl][j];      // row i0-1 value
                float hn, cn;
                CELL(U + ((tt + 1) * BW + bl) * 24,   // up (row i0-1), overwritten below
                     U + (tt * BW + bl) * 24,         // left (row i0, written at tt-1; slot0=0)
                     &fr[0][tt][bl][0], cu, clA, hn, cn);
                if (act) {
                    U[((tt + 1) * BW + bl) * 24 + j] = (_Float16)hn;
                    cBuf[tt][bl][j] = cn;
                }
            }
            if (tt >= 2) {   // cell B = (i1, tt-2)
                int u = tt - 2;
                float cu = cBuf[u][bl][j];       // row i0 value (A wrote it 2 steps ago)
                float hn, cn;
                CELL(U + ((u + 1) * BW + bl) * 24,    // up (row i0)
                     V + (u * BW + bl) * 24,          // left (row i1, written prev step)
                     &fr[1][u][bl][0], cu, clB, hn, cn);
                if (act) {
                    V[((u + 1) * BW + bl) * 24 + j] = (_Float16)hn;
                    cBuf[u][bl][j] = cn;
                }
            }
        }
        uv ^= 1;
    }
    // ---- solo row 14 ----
    {
        int fi0 = fh ? 0 : (GH - 1);
        for (int e = t; e < GW * BW * 6; e += 64) {
            int col = e / (BW * 6);
            int r2  = e % (BW * 6);
            int bb  = r2 / 6, w = r2 % 6;
            int bs  = blockIdx.x * BW + bb; if (bs >= NB) bs = NB - 1;
            int fcol = fw ? (GW - 1 - col) : col;
            ((unsigned*)fr)[(col * BW + bb) * 8 + w] =
                ((const unsigned*)featF)[((size_t)bs * 225 + fi0 * 15 + fcol) * 6 + w];
        }
        _Float16* U = &hBuf[uv][0][0][0];   // holds row 13
        float clA = 0.f;
        for (int tt = 0; tt < GW; ++tt) {
            float cu = cBuf[tt][bl][j];
            float hn, cn;
            CELL(U + ((tt + 1) * BW + bl) * 24,
                 U + (tt * BW + bl) * 24,
                 &fr[0][tt][bl][0], cu, clA, hn, cn);
            if (act) U[((tt + 1) * BW + bl) * 24 + j] = (_Float16)hn;
            if (bval && tt == GW - 1)
                corners[(size_t)bglob * 80 + d * HID + j] = hn;
        }
    }
}

// ---------------- Kernel 3: final FC [B,80] @ [80,10] + b ----------------
__global__ __launch_bounds__(256) void fc_kernel(
    const float* __restrict__ corners, // [B,80]
    const float* __restrict__ fc_w,    // [80,10]
    const float* __restrict__ fc_b,    // [10]
    float* __restrict__ out)           // [B,10]
{
    __shared__ float w[800];
    __shared__ float bb[10];
    int t = threadIdx.x;
    for (int e = t; e < 800; e += 256) w[e] = fc_w[e];
    if (t < 10) bb[t] = fc_b[t];
    __syncthreads();
    int gid = blockIdx.x * 256 + t;
    if (gid >= NB * 10) return;
    int b = gid / 10, o = gid % 10;
    float acc = bb[o];
    #pragma unroll 8
    for (int k = 0; k < 80; ++k)
        acc += corners[(size_t)b * 80 + k] * w[k * 10 + o];
    out[gid] = acc;
}

// ---------------- launcher ----------------
extern "C" void kernel_launch(void* const* d_in, const int* in_sizes, int n_in,
                              void* d_out, int out_size, void* d_ws, size_t ws_size,
                              hipStream_t stream) {
    const float* x      = (const float*)d_in[0];
    const float* conv_w = (const float*)d_in[1];
    const float* conv_b = (const float*)d_in[2];
    const float* Wx     = (const float*)d_in[3];
    const float* Whu    = (const float*)d_in[4];
    const float* Whl    = (const float*)d_in[5];
    const float* bg     = (const float*)d_in[6];
    const float* fc_w   = (const float*)d_in[7];
    const float* fc_b   = (const float*)d_in[8];
    float* out = (float*)d_out;

    half2v*    featH = (half2v*)d_ws;                       // B*225*6 half2 = 11.06 MB
    _Float16*  featF = (_Float16*)d_ws;
    float* corners   = (float*)d_ws + (size_t)NB * 225 * 6; // B*80 floats

    conv_pool_tanh<<<dim3((NB * 225 + 255) / 256), 256, 0, stream>>>(x, conv_w, conv_b, featH);
    mdlstm_scan<<<dim3((NB + BW - 1) / BW, 4), 64, 0, stream>>>(featF, Wx, Whu, Whl, bg, corners);
    fc_kernel<<<dim3((NB * 10 + 255) / 256), 256, 0, stream>>>(corners, fc_w, fc_b, out);
}

// Round 11
// 428.092 us; speedup vs baseline: 1.2918x; 1.0545x over previous
//
#include <hip/hip_runtime.h>
#include <math.h>

#define NB 2048
#define CINC 10
#define HID 20
#define NG 5
#define GDIM 100   // NG*HID
#define GH 15
#define GW 15
#define BW 3       // batch elems per wave (3*20 = 60 active lanes)

typedef _Float16 half2v __attribute__((ext_vector_type(2)));
typedef _Float16 half4v __attribute__((ext_vector_type(4)));
typedef _Float16 half8v __attribute__((ext_vector_type(8)));

#if defined(__has_builtin)
#if __has_builtin(__builtin_amdgcn_fdot2)
#define HAVE_FDOT2 1
#endif
#endif

__device__ __forceinline__ float fdot2f(half2v a, half2v b, float c) {
#ifdef HAVE_FDOT2
    return __builtin_amdgcn_fdot2(a, b, c, false);
#else
    return c + (float)a[0] * (float)b[0] + (float)a[1] * (float)b[1];
#endif
}

__device__ __forceinline__ float sigf(float x) {
    return __builtin_amdgcn_rcpf(1.f + __expf(-x));
}
__device__ __forceinline__ float tanhfast(float x) {
    // overflow-safe: e = exp(-2|x|) in (0,1], restore sign
    float ax = fabsf(x);
    float e = __expf(-2.f * ax);
    float t = (1.f - e) * __builtin_amdgcn_rcpf(1.f + e);
    return copysignf(t, x);
}

#define SV8(v, a, b) ((half2v)__builtin_shufflevector(v, v, a, b))
#define SV4(v, a, b) ((half2v)__builtin_shufflevector(v, v, a, b))

// ---- cell helpers: load operands / compute gates. All static-indexed -> registers. ----
__device__ __forceinline__ void cell_load(
    half2v (&up)[10], half2v (&lf)[10], half2v (&xp)[6], float& cu,
    const _Float16* hup, const _Float16* hlp, const _Float16* fxp, const float* cup)
{
    half8v u0 = *(const half8v*)(hup);
    half8v u1 = *(const half8v*)(hup + 8);
    half4v u2 = *(const half4v*)(hup + 16);
    half8v l0 = *(const half8v*)(hlp);
    half8v l1 = *(const half8v*)(hlp + 8);
    half4v l2 = *(const half4v*)(hlp + 16);
    half8v x0 = *(const half8v*)(fxp);
    half4v x1 = *(const half4v*)(fxp + 8);
    cu = *cup;
    up[0]=SV8(u0,0,1); up[1]=SV8(u0,2,3); up[2]=SV8(u0,4,5); up[3]=SV8(u0,6,7);
    up[4]=SV8(u1,0,1); up[5]=SV8(u1,2,3); up[6]=SV8(u1,4,5); up[7]=SV8(u1,6,7);
    up[8]=SV4(u2,0,1); up[9]=SV4(u2,2,3);
    lf[0]=SV8(l0,0,1); lf[1]=SV8(l0,2,3); lf[2]=SV8(l0,4,5); lf[3]=SV8(l0,6,7);
    lf[4]=SV8(l1,0,1); lf[5]=SV8(l1,2,3); lf[6]=SV8(l1,4,5); lf[7]=SV8(l1,6,7);
    lf[8]=SV4(l2,0,1); lf[9]=SV4(l2,2,3);
    xp[0]=SV8(x0,0,1); xp[1]=SV8(x0,2,3); xp[2]=SV8(x0,4,5); xp[3]=SV8(x0,6,7);
    xp[4]=SV4(x1,0,1); xp[5]=SV4(x1,2,3);
}

__device__ __forceinline__ void cell_comp(
    const half2v (&up)[10], const half2v (&lf)[10], const half2v (&xp)[6], float cu,
    const half2v (&wU)[10][NG], const half2v (&wL)[10][NG], const half2v (&wX)[6][NG],
    const float (&bgr)[NG], float& cl, float& hn, float& cn)
{
    float acc[NG];
    #pragma unroll
    for (int g = 0; g < NG; ++g) acc[g] = bgr[g];
    #pragma unroll
    for (int m = 0; m < 10; ++m)
        #pragma unroll
        for (int g = 0; g < NG; ++g) acc[g] = fdot2f(up[m], wU[m][g], acc[g]);
    #pragma unroll
    for (int m = 0; m < 10; ++m)
        #pragma unroll
        for (int g = 0; g < NG; ++g) acc[g] = fdot2f(lf[m], wL[m][g], acc[g]);
    #pragma unroll
    for (int w = 0; w < 6; ++w)
        #pragma unroll
        for (int g = 0; g < NG; ++g) acc[g] = fdot2f(xp[w], wX[w][g], acc[g]);
    float gi = sigf(acc[0]);
    float g1 = sigf(acc[1]);
    float g2 = sigf(acc[2]);
    float zz = tanhfast(acc[3]);
    float go = sigf(acc[4]);
    cn = g1 * cu + g2 * cl + gi * zz;
    hn = go * tanhfast(cn);
    cl = cn;
}

// ---------------- Kernel 1: conv3x3 + bias + maxpool2x2 + tanh -> f16 pairs ----------------
__global__ __launch_bounds__(256) void conv_pool_tanh(
    const float* __restrict__ x,
    const float* __restrict__ conv_w,
    const float* __restrict__ conv_b,
    half2v* __restrict__ featH)
{
    __shared__ float wl[270];
    __shared__ float bl[10];
    int tid = threadIdx.x;
    for (int e = tid; e < 270; e += 256) wl[e] = conv_w[e];
    if (tid < 10) bl[tid] = conv_b[tid];
    __syncthreads();
    int gid = blockIdx.x * 256 + tid;
    if (gid >= NB * 225) return;
    int b = gid / 225;
    int r = gid % 225;
    int i = r / 15, j = r % 15;
    const float* xb = x + (size_t)b * 3 * 1024;

    float win[3][4][4];
    #pragma unroll
    for (int ic = 0; ic < 3; ++ic)
        #pragma unroll
        for (int rr = 0; rr < 4; ++rr)
            #pragma unroll
            for (int cc = 0; cc < 4; ++cc)
                win[ic][rr][cc] = xb[ic * 1024 + (2 * i + rr) * 32 + (2 * j + cc)];

    float vals[10];
    #pragma unroll
    for (int oc = 0; oc < CINC; ++oc) {
        float a00, a01, a10, a11;
        a00 = a01 = a10 = a11 = bl[oc];
        #pragma unroll
        for (int ic = 0; ic < 3; ++ic)
            #pragma unroll
            for (int kr = 0; kr < 3; ++kr)
                #pragma unroll
                for (int kc = 0; kc < 3; ++kc) {
                    float w = wl[(oc * 3 + ic) * 9 + kr * 3 + kc];
                    a00 += win[ic][kr][kc]         * w;
                    a01 += win[ic][kr][kc + 1]     * w;
                    a10 += win[ic][kr + 1][kc]     * w;
                    a11 += win[ic][kr + 1][kc + 1] * w;
                }
        float m = fmaxf(fmaxf(a00, a01), fmaxf(a10, a11));
        vals[oc] = tanhfast(m);
    }
    half2v* fo = featH + (size_t)gid * 6;
    half2v w0; w0[0] = (_Float16)vals[0]; w0[1] = (_Float16)vals[1]; fo[0] = w0;
    half2v w1; w1[0] = (_Float16)vals[2]; w1[1] = (_Float16)vals[3]; fo[1] = w1;
    half2v w2; w2[0] = (_Float16)vals[4]; w2[1] = (_Float16)0.f;     fo[2] = w2;
    half2v w3; w3[0] = (_Float16)vals[5]; w3[1] = (_Float16)vals[6]; fo[3] = w3;
    half2v w4; w4[0] = (_Float16)vals[7]; w4[1] = (_Float16)vals[8]; fo[4] = w4;
    half2v w5; w5[0] = (_Float16)vals[9]; w5[1] = (_Float16)0.f;     fo[5] = w5;
}

// ---------------- Kernel 2: wave-private MD-LSTM scan, row-pair skew, MERGED body ----------------
// Block = 1 wave = (direction, 3-batch tile). lane = (b<3, j<20).
// Steady state: ONE basic block computes A=(i0,tt) and B=(i1,tt-2) together (loads first,
// two independent dot chains, stores last) so the scheduler can interleave the chains.
// R10 lesson: separate if-blocks (uniform branches) prevented any interleave.
// No min-waves clause (R9 lesson: a 170-VGPR cap demotes the weight arrays to scratch).
__global__ __launch_bounds__(64) void mdlstm_scan(
    const _Float16* __restrict__ featF,   // [B,225,12] halves (16/slot)
    const float* __restrict__ Wx,         // [4,10,100]
    const float* __restrict__ Whu,        // [4,20,100]
    const float* __restrict__ Whl,        // [4,20,100]
    const float* __restrict__ bg,         // [4,100]
    float* __restrict__ corners)          // [B,80]
{
    int t = threadIdx.x;
    int b = t / HID;              // 0..2 active
    int j = t % HID;
    bool act = (t < BW * HID);
    int bl = act ? b : 0;
    const int blo = bl * 24;
    int d = blockIdx.y;
    int bglob = blockIdx.x * BW + b;
    bool bval = act && (bglob < NB);
    int fh = (d == 1 || d == 3);
    int fw = (d == 2 || d == 3);

    // ---- f16-packed weights in registers (135 VGPR) ----
    half2v wU[10][NG], wL[10][NG], wX2[6][NG];
    {
        const float* WU = Whu + d * HID * GDIM;
        const float* WL = Whl + d * HID * GDIM;
        #pragma unroll
        for (int m = 0; m < 10; ++m)
            #pragma unroll
            for (int g = 0; g < NG; ++g) {
                int cidx = g * HID + j;
                half2v w; w[0] = (_Float16)WU[(2*m)*GDIM + cidx]; w[1] = (_Float16)WU[(2*m+1)*GDIM + cidx];
                wU[m][g] = w;
                half2v v; v[0] = (_Float16)WL[(2*m)*GDIM + cidx]; v[1] = (_Float16)WL[(2*m+1)*GDIM + cidx];
                wL[m][g] = v;
            }
        const int cha[6] = {0, 2, 4, 5, 7, 9};
        const int chb[6] = {1, 3, -1, 6, 8, -1};
        const float* WXp = Wx + d * CINC * GDIM;
        #pragma unroll
        for (int w = 0; w < 6; ++w)
            #pragma unroll
            for (int g = 0; g < NG; ++g) {
                int cidx = g * HID + j;
                half2v v;
                v[0] = (_Float16)WXp[cha[w] * GDIM + cidx];
                v[1] = (chb[w] >= 0) ? (_Float16)WXp[chb[w] * GDIM + cidx] : (_Float16)0.f;
                wX2[w][g] = v;
            }
    }
    float bgr[NG];
    #pragma unroll
    for (int g = 0; g < NG; ++g) bgr[g] = bg[d * GDIM + g * HID + j];

    // ---- LDS (11.1 KB) ----
    __shared__ _Float16 hBuf[2][GW + 1][BW][24];  // slot 0 = permanent zeros
    __shared__ float    cBuf[GW][BW][HID];        // in-place per column
    __shared__ _Float16 fr[2][GW][BW][16];        // two staged feat rows

    for (int e = t; e < 2 * (GW + 1) * BW * 24; e += 64) (&hBuf[0][0][0][0])[e] = (_Float16)0.f;
    for (int e = t; e < GW * BW * HID; e += 64) (&cBuf[0][0][0])[e] = 0.f;

    int uv = 0;
    for (int r = 0; r < 7; ++r) {
        int i0 = 2 * r, i1 = 2 * r + 1;
        // stage feat rows i0, i1 (W-flip applied)
        {
            int fi0 = fh ? (GH - 1 - i0) : i0;
            int fi1 = fh ? (GH - 1 - i1) : i1;
            for (int e = t; e < 2 * GW * BW * 6; e += 64) {
                int fb  = e / (GW * BW * 6);
                int rem = e % (GW * BW * 6);
                int col = rem / (BW * 6);
                int r2  = rem % (BW * 6);
                int bb  = r2 / 6, w = r2 % 6;
                int bs  = blockIdx.x * BW + bb; if (bs >= NB) bs = NB - 1;
                int fcol = fw ? (GW - 1 - col) : col;
                int fi  = fb ? fi1 : fi0;
                ((unsigned*)fr)[(fb * GW * BW + col * BW + bb) * 8 + w] =
                    ((const unsigned*)featF)[((size_t)bs * 225 + fi * 15 + fcol) * 6 + w];
            }
        }
        _Float16* U = &hBuf[uv][0][0][0];       // row i0-1, overwritten in place with row i0
        _Float16* V = &hBuf[uv ^ 1][0][0][0];   // receives row i1
        float clA = 0.f, clB = 0.f;

        // ---- prologue: A(0), A(1) ----
        #pragma unroll
        for (int tt = 0; tt < 2; ++tt) {
            half2v upA[10], lfA[10], xpA[6]; float cuA;
            cell_load(upA, lfA, xpA, cuA,
                      U + (tt + 1) * 72 + blo, U + tt * 72 + blo,
                      &fr[0][tt][bl][0], &cBuf[tt][bl][j]);
            float hnA, cnA;
            cell_comp(upA, lfA, xpA, cuA, wU, wL, wX2, bgr, clA, hnA, cnA);
            if (act) {
                U[(tt + 1) * 72 + blo + j] = (_Float16)hnA;
                cBuf[tt][bl][j] = cnA;
            }
        }
        // ---- steady: A(tt) + B(tt-2) in one basic block ----
        #pragma unroll 1
        for (int tt = 2; tt < GW; ++tt) {
            int u = tt - 2;
            half2v upA[10], lfA[10], xpA[6]; float cuA;
            half2v upB[10], lfB[10], xpB[6]; float cuB;
            cell_load(upA, lfA, xpA, cuA,
                      U + (tt + 1) * 72 + blo, U + tt * 72 + blo,
                      &fr[0][tt][bl][0], &cBuf[tt][bl][j]);
            cell_load(upB, lfB, xpB, cuB,
                      U + (u + 1) * 72 + blo, V + u * 72 + blo,
                      &fr[1][u][bl][0], &cBuf[u][bl][j]);
            float hnA, cnA, hnB, cnB;
            cell_comp(upA, lfA, xpA, cuA, wU, wL, wX2, bgr, clA, hnA, cnA);
            cell_comp(upB, lfB, xpB, cuB, wU, wL, wX2, bgr, clB, hnB, cnB);
            if (act) {
                U[(tt + 1) * 72 + blo + j] = (_Float16)hnA;
                cBuf[tt][bl][j] = cnA;
                V[(u + 1) * 72 + blo + j] = (_Float16)hnB;
                cBuf[u][bl][j] = cnB;
            }
        }
        // ---- epilogue: B(13), B(14) ----
        #pragma unroll
        for (int u = GW - 2; u < GW; ++u) {
            half2v upB[10], lfB[10], xpB[6]; float cuB;
            cell_load(upB, lfB, xpB, cuB,
                      U + (u + 1) * 72 + blo, V + u * 72 + blo,
                      &fr[1][u][bl][0], &cBuf[u][bl][j]);
            float hnB, cnB;
            cell_comp(upB, lfB, xpB, cuB, wU, wL, wX2, bgr, clB, hnB, cnB);
            if (act) {
                V[(u + 1) * 72 + blo + j] = (_Float16)hnB;
                cBuf[u][bl][j] = cnB;
            }
        }
        uv ^= 1;
    }
    // ---- solo row 14 ----
    {
        int fi0 = fh ? 0 : (GH - 1);
        for (int e = t; e < GW * BW * 6; e += 64) {
            int col = e / (BW * 6);
            int r2  = e % (BW * 6);
            int bb  = r2 / 6, w = r2 % 6;
            int bs  = blockIdx.x * BW + bb; if (bs >= NB) bs = NB - 1;
            int fcol = fw ? (GW - 1 - col) : col;
            ((unsigned*)fr)[(col * BW + bb) * 8 + w] =
                ((const unsigned*)featF)[((size_t)bs * 225 + fi0 * 15 + fcol) * 6 + w];
        }
        _Float16* U = &hBuf[uv][0][0][0];   // holds row 13
        float clA = 0.f;
        for (int tt = 0; tt < GW; ++tt) {
            half2v upA[10], lfA[10], xpA[6]; float cuA;
            cell_load(upA, lfA, xpA, cuA,
                      U + (tt + 1) * 72 + blo, U + tt * 72 + blo,
                      &fr[0][tt][bl][0], &cBuf[tt][bl][j]);
            float hnA, cnA;
            cell_comp(upA, lfA, xpA, cuA, wU, wL, wX2, bgr, clA, hnA, cnA);
            if (act) U[(tt + 1) * 72 + blo + j] = (_Float16)hnA;
            if (bval && tt == GW - 1)
                corners[(size_t)bglob * 80 + d * HID + j] = hnA;
        }
    }
}

// ---------------- Kernel 3: final FC [B,80] @ [80,10] + b ----------------
__global__ __launch_bounds__(256) void fc_kernel(
    const float* __restrict__ corners, // [B,80]
    const float* __restrict__ fc_w,    // [80,10]
    const float* __restrict__ fc_b,    // [10]
    float* __restrict__ out)           // [B,10]
{
    __shared__ float w[800];
    __shared__ float bb[10];
    int t = threadIdx.x;
    for (int e = t; e < 800; e += 256) w[e] = fc_w[e];
    if (t < 10) bb[t] = fc_b[t];
    __syncthreads();
    int gid = blockIdx.x * 256 + t;
    if (gid >= NB * 10) return;
    int b = gid / 10, o = gid % 10;
    float acc = bb[o];
    #pragma unroll 8
    for (int k = 0; k < 80; ++k)
        acc += corners[(size_t)b * 80 + k] * w[k * 10 + o];
    out[gid] = acc;
}

// ---------------- launcher ----------------
extern "C" void kernel_launch(void* const* d_in, const int* in_sizes, int n_in,
                              void* d_out, int out_size, void* d_ws, size_t ws_size,
                              hipStream_t stream) {
    const float* x      = (const float*)d_in[0];
    const float* conv_w = (const float*)d_in[1];
    const float* conv_b = (const float*)d_in[2];
    const float* Wx     = (const float*)d_in[3];
    const float* Whu    = (const float*)d_in[4];
    const float* Whl    = (const float*)d_in[5];
    const float* bg     = (const float*)d_in[6];
    const float* fc_w   = (const float*)d_in[7];
    const float* fc_b   = (const float*)d_in[8];
    float* out = (float*)d_out;

    half2v*    featH = (half2v*)d_ws;                       // B*225*6 half2 = 11.06 MB
    _Float16*  featF = (_Float16*)d_ws;
    float* corners   = (float*)d_ws + (size_t)NB * 225 * 6; // B*80 floats

    conv_pool_tanh<<<dim3((NB * 225 + 255) / 256), 256, 0, stream>>>(x, conv_w, conv_b, featH);
    mdlstm_scan<<<dim3((NB + BW - 1) / BW, 4), 64, 0, stream>>>(featF, Wx, Whu, Whl, bg, corners);
    fc_kernel<<<dim3((NB * 10 + 255) / 256), 256, 0, stream>>>(corners, fc_w, fc_b, out);
}